// Round 12
// baseline (556.733 us; speedup 1.0000x reference)
//
#include <hip/hip_runtime.h>
#include <hip/hip_bf16.h>
#include <hip/hip_cooperative_groups.h>
#include <math.h>

namespace cg = cooperative_groups;

#define HID 512
#define HEADS 8
#define HD 64
#define L 512
#define B 2
#define PF 2048
#define EPS 1e-5f
#define LOG2E 1.4426950408889634f

// degree-5 odd tanh fit on [-0.8,0.8], max err ~2e-4 in range
#define TD1 0.999253f
#define TD3 -0.321476f
#define TD5 0.089206f

typedef short v8s __attribute__((ext_vector_type(8)));
typedef short v4s __attribute__((ext_vector_type(4)));
typedef float f32x4 __attribute__((ext_vector_type(4)));
typedef unsigned short u16;

// async global->LDS, 16B per lane; LDS dest = wave-uniform base + lane*16
#define GL2LDS16(gp, lp) __builtin_amdgcn_global_load_lds( \
    (const __attribute__((address_space(1))) unsigned int*)(gp), \
    (__attribute__((address_space(3))) unsigned int*)(lp), 16, 0, 0)

__device__ __forceinline__ u16 f2bf(float f) {
  union { float f; unsigned u; } v;
  v.f = f;
  unsigned r = v.u + 0x7FFFu + ((v.u >> 16) & 1u);
  return (u16)(r >> 16);
}

__device__ __forceinline__ float bf2f(u16 b) {
  union { unsigned u; float f; } v;
  v.u = ((unsigned)b) << 16;
  return v.f;
}

// ===========================================================================
// Shared device bodies (used by mega-kernel AND standalone fallback kernels)
// ===========================================================================

// 64x64-tile MFMA GEMM tile, 3-deep LDS pipeline + counted vmcnt.
// smem arena: Al at 0 (24KB), Bl at 24576 (24KB).
template <int EPI, bool RELU>
__device__ void gemm_body(char* smem, int bx, int by, int z,
    const u16* __restrict__ A0, const u16* __restrict__ W0,
    const float* __restrict__ ba, const float* __restrict__ bb,
    const float* __restrict__ bc, const float* __restrict__ vwp,
    float* __restrict__ outf, u16* __restrict__ outb,
    int N, int ldA, int ldW, long stepA, long stepW, int nsteps, int zA) {
  auto Al = (u16 (*)[8][64][8])smem;           // [3][8][64][8]
  auto Bl = (u16 (*)[8][64][8])(smem + 24576); // [3][8][64][8]
  const int t = threadIdx.x;
  const u16* A = A0;
  const u16* W = W0;
  float* of = outf;
  u16* ob = outb;
  if (EPI == 5) {
    A += (size_t)z * 32768;   // z*512 rows within plane (ld 64)
    W += (size_t)z * 32768;
    ob += (size_t)z * 262144;
  } else if (EPI == 6) {
    A += (size_t)z * zA;      // K offset
    W += (size_t)z * zA;
    of += (size_t)z * 524288; // partial buffer
  }

  const int bm = by * 64, bn = bx * 64;
  const int lane = t & 63, wv = t >> 6;
  const int wr = wv >> 1, wc = wv & 1;
  const int lg = lane >> 4, lr = lane & 15;

  const u16* Asrc = A + (size_t)(bm + lane) * ldA + wv * 8;
  const u16* Bsrc = W + (size_t)(bn + lane) * ldW + wv * 8;

  f32x4 zero = {0.f, 0.f, 0.f, 0.f};
  f32x4 acc[2][2] = {{zero, zero}, {zero, zero}};

  __syncthreads();  // LDS arena handoff from previous stage/tile

#define STAGE(tt) do {                                   \
    const long oA = (long)(tt) * stepA;                  \
    const long oW = (long)(tt) * stepW;                  \
    const int bi_ = (tt) % 3;                            \
    GL2LDS16(Asrc + oA,      &Al[bi_][wv][0][0]);        \
    GL2LDS16(Asrc + oA + 32, &Al[bi_][wv + 4][0][0]);    \
    GL2LDS16(Bsrc + oW,      &Bl[bi_][wv][0][0]);        \
    GL2LDS16(Bsrc + oW + 32, &Bl[bi_][wv + 4][0][0]);    \
  } while (0)

  STAGE(0);
  if (nsteps > 1) STAGE(1);

  for (int s = 0; s < nsteps; s++) {
    if (s + 1 < nsteps) {
      asm volatile("s_waitcnt vmcnt(4)" ::: "memory");
    } else {
      asm volatile("s_waitcnt vmcnt(0)" ::: "memory");
    }
    __builtin_amdgcn_s_barrier();
    if (s + 2 < nsteps) STAGE(s + 2);

    const int cur = s % 3;
    #pragma unroll
    for (int hf = 0; hf < 2; hf++) {
      v8s a0 = *(const v8s*)&Al[cur][hf * 4 + lg][wr * 32 + lr][0];
      v8s a1 = *(const v8s*)&Al[cur][hf * 4 + lg][wr * 32 + 16 + lr][0];
      v8s b0 = *(const v8s*)&Bl[cur][hf * 4 + lg][wc * 32 + lr][0];
      v8s b1 = *(const v8s*)&Bl[cur][hf * 4 + lg][wc * 32 + 16 + lr][0];
      acc[0][0] = __builtin_amdgcn_mfma_f32_16x16x32_bf16(a0, b0, acc[0][0], 0, 0, 0);
      acc[0][1] = __builtin_amdgcn_mfma_f32_16x16x32_bf16(a0, b1, acc[0][1], 0, 0, 0);
      acc[1][0] = __builtin_amdgcn_mfma_f32_16x16x32_bf16(a1, b0, acc[1][0], 0, 0, 0);
      acc[1][1] = __builtin_amdgcn_mfma_f32_16x16x32_bf16(a1, b1, acc[1][1], 0, 0, 0);
    }
  }
#undef STAGE

  #pragma unroll
  for (int m = 0; m < 2; m++) {
    #pragma unroll
    for (int n = 0; n < 2; n++) {
      const int gm0 = bm + wr * 32 + m * 16 + lg * 4;
      const int gn = bn + wc * 32 + n * 16 + lr;
      if (EPI == 0) {
        const float bvv = ba[gn];
        #pragma unroll
        for (int r = 0; r < 4; r++)
          of[(size_t)(gm0 + r) * N + gn] = acc[m][n][r] + bvv;
      } else if (EPI == 1) {
        const float bvv = ba[gn];
        #pragma unroll
        for (int r = 0; r < 4; r++) {
          float v = acc[m][n][r] + bvv;
          if (RELU) v = fmaxf(v, 0.f);
          ob[(size_t)(gm0 + r) * N + gn] = f2bf(v);
        }
      } else if (EPI == 2) {
        const int region = bn >> 9;  // uniform per block
        const int np = gn & 511, h = np >> 6, d = np & 63;
        const int b_ = gm0 >> 9, q0 = gm0 & 511;
        const int bh = b_ * 8 + h;
        if (region == 0) {
          const float bvv = ba[np];
          #pragma unroll
          for (int r = 0; r < 4; r++) {
            const float u = acc[m][n][r] + bvv;
            const float u2 = u * u;
            const size_t base = ((size_t)bh * 512 + q0 + r) * 64 + d;
            ob[base + 524288]  = f2bf(u);
            ob[base + 1048576] = f2bf(u2);
            ob[base + 1572864] = f2bf(u2 * u);
            ob[base + 2097152] = f2bf(u2 * u2);
          }
        } else if (region == 1) {
          const float bvv = bb[np];
          const float w = vwp[d];
          u16* kf = ob + 2621440;  // Kf base (5 planes after Qf)
          #pragma unroll
          for (int r = 0; r < 4; r++) {
            const float v = acc[m][n][r] + bvv;
            const float v2 = v * v;
            const size_t base = ((size_t)bh * 512 + q0 + r) * 64 + d;
            kf[base]           = f2bf(w * v * fmaf(v2, fmaf(v2, TD5, TD3), TD1));
            kf[base + 524288]  = f2bf(w * fmaf(v2, fmaf(v2, 5.f * TD5, 3.f * TD3), TD1));
            kf[base + 1048576] = f2bf(w * v * fmaf(v2, 10.f * TD5, 3.f * TD3));
            kf[base + 1572864] = f2bf(w * fmaf(v2, 10.f * TD5, TD3));
            kf[base + 2097152] = f2bf(w * 5.f * TD5 * v);
          }
        } else {
          const float bvv = bc[np];
          u16* vt = (u16*)outf;
          v4s pk;
          #pragma unroll
          for (int r = 0; r < 4; r++) pk[r] = (short)f2bf(acc[m][n][r] + bvv);
          *(v4s*)&vt[((size_t)bh * 64 + d) * 512 + q0] = pk;
        }
      } else if (EPI == 5) {
        #pragma unroll
        for (int r = 0; r < 4; r++)
          ob[(size_t)(gm0 + r) * 512 + gn] = f2bf(acc[m][n][r]);
      } else {  // EPI == 6
        const float bvv = (z == 0) ? ba[gn] : 0.f;
        #pragma unroll
        for (int r = 0; r < 4; r++)
          of[(size_t)(gm0 + r) * 512 + gn] = acc[m][n][r] + bvv;
      }
    }
  }
}

// Fused softmax + PV tile (32 q-rows x one bh).
// smem arena: P at 0 (32KB), Bl at 32768 (16KB).
__device__ void attn_body(char* smem, int qt, int bh,
    const u16* __restrict__ energy, const u16* __restrict__ VT,
    const int* __restrict__ mask, u16* __restrict__ attno) {
  auto P = (u16 (*)[512])smem;                    // [32][512]
  auto Bl = (u16 (*)[8][64][8])(smem + 32768);    // [2][8][64][8]
  const int b = bh >> 3, h = bh & 7;
  const int t = threadIdx.x;
  const int lane = t & 63, wv = t >> 6;

  __syncthreads();  // arena handoff

  const u16* eb = energy + ((size_t)bh * 512 + qt * 32) * 512;
  const int mbase = b * 512 + lane * 8;
  #pragma unroll
  for (int rr = 0; rr < 8; rr++) {
    const int r = wv * 8 + rr;
    v8s ev = *(const v8s*)&eb[(size_t)r * 512 + lane * 8];
    float e[8];
    float mx = -INFINITY;
    #pragma unroll
    for (int i = 0; i < 8; i++) {
      float x = bf2f((u16)ev[i]);
      if (mask[mbase + i] == 0) x = -INFINITY;
      e[i] = x;
      mx = fmaxf(mx, x);
    }
    #pragma unroll
    for (int off = 32; off > 0; off >>= 1) mx = fmaxf(mx, __shfl_xor(mx, off));
    float sm = 0.f;
    #pragma unroll
    for (int i = 0; i < 8; i++) {
      e[i] = exp2f((e[i] - mx) * LOG2E);
      sm += e[i];
    }
    #pragma unroll
    for (int off = 32; off > 0; off >>= 1) sm += __shfl_xor(sm, off);
    const float inv = __builtin_amdgcn_rcpf(sm);
    v8s po;
    #pragma unroll
    for (int i = 0; i < 8; i++) po[i] = (short)f2bf(e[i] * inv);
    *(v8s*)&P[r][(lane ^ (r & 7)) * 8] = po;   // slot swizzle
  }
  __syncthreads();

  const int wr = wv >> 1, wc = wv & 1;
  const int lg = lane >> 4, lr = lane & 15;
  f32x4 acc0 = {0.f, 0.f, 0.f, 0.f}, acc1 = acc0;
  const u16* Bsrc = VT + ((size_t)bh * 64 + lane) * 512 + wv * 8;

  GL2LDS16(Bsrc,      &Bl[0][wv][0][0]);
  GL2LDS16(Bsrc + 32, &Bl[0][wv + 4][0][0]);
  __syncthreads();

  const int arow = wr * 16 + lr;
  const int axor = arow & 7;
  for (int s = 0; s < 8; s++) {
    const int cur = s & 1;
    if (s < 7) {
      const int k0 = (s + 1) << 6;
      GL2LDS16(Bsrc + k0,      &Bl[cur ^ 1][wv][0][0]);
      GL2LDS16(Bsrc + k0 + 32, &Bl[cur ^ 1][wv + 4][0][0]);
    }
    #pragma unroll
    for (int hf = 0; hf < 2; hf++) {
      const int bslot = s * 8 + hf * 4 + lg;
      v8s a = *(const v8s*)&P[arow][(bslot ^ axor) * 8];
      v8s b0 = *(const v8s*)&Bl[cur][hf * 4 + lg][wc * 32 + lr][0];
      v8s b1 = *(const v8s*)&Bl[cur][hf * 4 + lg][wc * 32 + 16 + lr][0];
      acc0 = __builtin_amdgcn_mfma_f32_16x16x32_bf16(a, b0, acc0, 0, 0, 0);
      acc1 = __builtin_amdgcn_mfma_f32_16x16x32_bf16(a, b1, acc1, 0, 0, 0);
    }
    __syncthreads();
  }

  const int q0 = qt * 32 + wr * 16 + lg * 4;
  #pragma unroll
  for (int n = 0; n < 2; n++) {
    f32x4 a = n ? acc1 : acc0;
    const int d = wc * 32 + n * 16 + lr;
    #pragma unroll
    for (int r = 0; r < 4; r++)
      attno[((size_t)(b * 512 + q0 + r)) * 512 + h * 64 + d] = f2bf(a[r]);
  }
}

// Residual + LayerNorm of one row; x = sum of NX partials (stride 524288).
template <bool DUAL, int NX>
__device__ void ln_body(char* smem, int row,
    const float* __restrict__ x, const float* __restrict__ res,
    const float* __restrict__ g, const float* __restrict__ bt,
    float* __restrict__ outf, u16* __restrict__ outb) {
  float* rs = (float*)smem;
  float* rss = rs + 256;
  const int t = threadIdx.x;
  const float* rr = res + (size_t)row * HID;

  float v0 = rr[t];
  float v1 = rr[t + 256];
  #pragma unroll
  for (int i = 0; i < NX; i++) {
    const float* xr = x + (size_t)i * 524288 + (size_t)row * HID;
    v0 += xr[t];
    v1 += xr[t + 256];
  }

  __syncthreads();  // arena handoff / previous row done
  rs[t] = v0 + v1;
  rss[t] = v0 * v0 + v1 * v1;
  __syncthreads();
  for (int off = 128; off > 0; off >>= 1) {
    if (t < off) {
      rs[t] += rs[t + off];
      rss[t] += rss[t + off];
    }
    __syncthreads();
  }
  const float mean = rs[0] * (1.f / HID);
  const float var = rss[0] * (1.f / HID) - mean * mean;
  const float inv = rsqrtf(var + EPS);

  float o0 = (v0 - mean) * inv * g[t] + bt[t];
  float o1 = (v1 - mean) * inv * g[t + 256] + bt[t + 256];
  outf[(size_t)row * HID + t] = o0;
  outf[(size_t)row * HID + t + 256] = o1;
  if (DUAL) {
    outb[(size_t)row * HID + t] = f2bf(o0);
    outb[(size_t)row * HID + t + 256] = f2bf(o1);
  }
}

// ===========================================================================
// Cooperative mega-kernel
// ===========================================================================
struct P24 {
  const float* src; const int* mask;
  const float *Wq, *bq, *Wk, *bk, *Wv, *bv, *Ww, *bw, *Wu, *bu, *vw, *vb;
  const float *Wo, *bo, *g1, *b1n, *g2, *b2n, *W1, *bf1, *W2, *bf2;
  float* out; char* ws;
};

#define MEGA_GRID 512

__global__ __launch_bounds__(256, 2) void mega(P24 p) {
  cg::grid_group grid = cg::this_grid();
  __shared__ __align__(16) char smem[49152];
  const int bid = blockIdx.x;
  const int t = threadIdx.x;

  char* wsb = p.ws;
  const size_t MB = 1024 * 1024;
  u16*   srcb  = (u16*)(wsb);
  u16*   Wcat  = (u16*)(wsb + 1 * MB);
  u16*   Wqp   = Wcat;
  u16*   Wkp   = Wcat + 262144;
  u16*   Wvb   = Wcat + 524288;
  u16*   Wob   = (u16*)(wsb + 5 * MB / 2);
  u16*   W1b   = (u16*)(wsb + 3 * MB);
  u16*   W2b   = (u16*)(wsb + 5 * MB);
  float* bqp   = (float*)(wsb + 7 * MB);
  float* bkp   = (float*)(wsb + 7 * MB + 8192);
  u16*   VT    = (u16*)(wsb + 8 * MB);
  u16*   Qf    = (u16*)(wsb + 9 * MB);
  u16*   Kf    = (u16*)(wsb + 14 * MB);
  u16*   energyb = (u16*)(wsb + 19 * MB);
  u16*   attno = (u16*)(wsb + 27 * MB);
  float* woout = (float*)(wsb + 28 * MB);   // 2 partials (4MB)
  float* ln1f  = (float*)(wsb + 32 * MB);
  u16*   ln1b  = (u16*)(wsb + 34 * MB);
  u16*   hb    = (u16*)(wsb + 35 * MB);
  float* ffn2f = (float*)(wsb + 39 * MB);   // 4 partials (8MB)

  // --- S0: prep (convert, ones-plane, weight-fold) ---
  {
    const float* S[5] = {p.src, p.Wv, p.Wo, p.W1, p.W2};
    u16* D[5] = {srcb, Wvb, Wob, W1b, W2b};
    const int NV[5] = {131072, 65536, 65536, 262144, 262144};  // v4 units
    #pragma unroll
    for (int sg = 0; sg < 5; sg++) {
      for (int i = bid * 256 + t; i < NV[sg]; i += MEGA_GRID * 256) {
        float4 v = *(const float4*)&S[sg][(size_t)i * 4];
        v4s o;
        o[0] = (short)f2bf(v.x); o[1] = (short)f2bf(v.y);
        o[2] = (short)f2bf(v.z); o[3] = (short)f2bf(v.w);
        *(v4s*)&D[sg][(size_t)i * 4] = o;
      }
    }
    for (int i = bid * 256 + t; i < 131072; i += MEGA_GRID * 256) {
      v4s o;
      o[0] = o[1] = o[2] = o[3] = (short)0x3F80;
      *(v4s*)&Qf[(size_t)i * 4] = o;
    }
    float* wrow = (float*)smem;
    for (int u = 0; u < 2; u++) {
      const int unit = bid + MEGA_GRID * u;   // 0..1023
      const int hi = unit & 511, h = hi >> 6, i = hi & 63;
      const bool isK = unit >= 512;
      const float* Ws = isK ? p.Wu : p.Ww;
      const float* Wb = isK ? p.Wk : p.Wq;
      const float* bs = isK ? p.bu : p.bw;
      const float* bb2 = isK ? p.bk : p.bq;
      u16* ow = isK ? Wkp : Wqp;
      float* ob = isK ? bkp : bqp;
      __syncthreads();
      if (t < 64) wrow[t] = Ws[i * 64 + t];
      __syncthreads();
      float a0 = 0.f, a1 = 0.f;
      for (int j = 0; j < 64; j++) {
        const float w = wrow[j];
        a0 = fmaf(w, Wb[(size_t)(h * 64 + j) * 512 + t], a0);
        a1 = fmaf(w, Wb[(size_t)(h * 64 + j) * 512 + t + 256], a1);
      }
      ow[(size_t)hi * 512 + t] = f2bf(a0);
      ow[(size_t)hi * 512 + t + 256] = f2bf(a1);
      if (t == 0) {
        float s2 = bs[i];
        for (int j = 0; j < 64; j++) s2 = fmaf(wrow[j], bb2[h * 64 + j], s2);
        ob[hi] = s2;
      }
    }
  }
  grid.sync();

  // --- S1: fused projection (384 tiles) ---
  if (bid < 384)
    gemm_body<2, false>(smem, bid % 24, bid / 24, 0, srcb, Wcat, bqp, bkp,
                        p.bv, p.vw, (float*)VT, Qf, 1536, 512, 512, 64, 64, 8, 0);
  grid.sync();

  // --- S2: energy (1024 tiles, 2 per block) ---
  for (int i = 0; i < 2; i++) {
    const int T = bid + MEGA_GRID * i;
    gemm_body<5, false>(smem, T & 7, (T >> 3) & 7, T >> 6, Qf, Kf, nullptr,
                        nullptr, nullptr, nullptr, nullptr, energyb,
                        512, 64, 64, 524288, 524288, 5, 0);
  }
  grid.sync();

  // --- S3: softmax + PV (256 tiles) ---
  if (bid < 256)
    attn_body(smem, bid & 15, bid >> 4, energyb, VT, p.mask, attno);
  grid.sync();

  // --- S4: Wo, K-split z=2 (256 tiles) ---
  if (bid < 256)
    gemm_body<6, false>(smem, bid & 7, (bid >> 3) & 15, bid >> 7, attno, Wob,
                        p.bo, nullptr, nullptr, nullptr, woout, nullptr,
                        512, 512, 512, 64, 64, 4, 256);
  grid.sync();

  // --- S5: residual + LN1 (1024 rows) ---
  for (int r = 0; r < 2; r++)
    ln_body<true, 2>(smem, bid * 2 + r, woout, p.src, p.g1, p.b1n, ln1f, ln1b);
  grid.sync();

  // --- S6: FFN1 (512 tiles) ---
  gemm_body<1, true>(smem, bid & 31, bid >> 5, 0, ln1b, W1b, p.bf1, nullptr,
                     nullptr, nullptr, nullptr, hb, 2048, 512, 512, 64, 64, 8, 0);
  grid.sync();

  // --- S7: FFN2, K-split z=4 (512 tiles) ---
  gemm_body<6, false>(smem, bid & 7, (bid >> 3) & 15, bid >> 7, hb, W2b,
                      p.bf2, nullptr, nullptr, nullptr, ffn2f, nullptr,
                      512, 2048, 2048, 64, 64, 8, 512);
  grid.sync();

  // --- S8: residual + LN2 (1024 rows) ---
  for (int r = 0; r < 2; r++)
    ln_body<false, 4>(smem, bid * 2 + r, ffn2f, ln1f, p.g2, p.b2n, p.out, nullptr);
}

// ===========================================================================
// Standalone fallback kernels (R11 structure)
// ===========================================================================
__global__ __launch_bounds__(256) void prep_all(
    const float* __restrict__ s0, const float* __restrict__ s1,
    const float* __restrict__ s2, const float* __restrict__ s3,
    const float* __restrict__ s4,
    u16* d0, u16* d1, u16* d2, u16* d3, u16* d4,
    const float* __restrict__ Ww, const float* __restrict__ Wq,
    const float* __restrict__ bw, const float* __restrict__ bq,
    const float* __restrict__ Wu, const float* __restrict__ Wk,
    const float* __restrict__ bu, const float* __restrict__ bk,
    u16* __restrict__ Wqp, u16* __restrict__ Wkp,
    float* __restrict__ bqp, float* __restrict__ bkp,
    u16* __restrict__ Qf) {
  const int y = blockIdx.y;
  const int t = threadIdx.x;
  if (y < 5) {
    const float* s; u16* d; int n;
    switch (y) {
      case 0: s = s0; d = d0; n = 524288; break;
      case 1: s = s1; d = d1; n = 262144; break;
      case 2: s = s2; d = d2; n = 262144; break;
      case 3: s = s3; d = d3; n = 1048576; break;
      default: s = s4; d = d4; n = 1048576; break;
    }
    int idx = (blockIdx.x * 256 + t) * 4;
    if (idx >= n) return;
    float4 v = *(const float4*)&s[idx];
    v4s o;
    o[0] = (short)f2bf(v.x); o[1] = (short)f2bf(v.y);
    o[2] = (short)f2bf(v.z); o[3] = (short)f2bf(v.w);
    *(v4s*)&d[idx] = o;
  } else if (y < 7) {
    const int hi = blockIdx.x;
    if (hi >= 512) return;
    const int h = hi >> 6, i = hi & 63;
    const bool isK = (y == 6);
    const float* Ws = isK ? Wu : Ww;
    const float* Wb = isK ? Wk : Wq;
    const float* bs = isK ? bu : bw;
    const float* bb2 = isK ? bk : bq;
    u16* ow = isK ? Wkp : Wqp;
    float* ob = isK ? bkp : bqp;
    __shared__ float wrow[64];
    if (t < 64) wrow[t] = Ws[i * 64 + t];
    __syncthreads();
    float a0 = 0.f, a1 = 0.f;
    for (int j = 0; j < 64; j++) {
      const float w = wrow[j];
      a0 = fmaf(w, Wb[(size_t)(h * 64 + j) * 512 + t], a0);
      a1 = fmaf(w, Wb[(size_t)(h * 64 + j) * 512 + t + 256], a1);
    }
    ow[(size_t)hi * 512 + t] = f2bf(a0);
    ow[(size_t)hi * 512 + t + 256] = f2bf(a1);
    if (t == 0) {
      float s = bs[i];
      for (int j = 0; j < 64; j++) s = fmaf(wrow[j], bb2[h * 64 + j], s);
      ob[hi] = s;
    }
  } else {
    int idx = (blockIdx.x * 256 + t) * 4;
    if (idx >= 524288) return;
    v4s o;
    o[0] = o[1] = o[2] = o[3] = (short)0x3F80;
    *(v4s*)&Qf[idx] = o;
  }
}

template <int EPI, bool RELU>
__global__ __launch_bounds__(256) void gemm64(
    const u16* __restrict__ A0, const u16* __restrict__ W0,
    const float* __restrict__ ba, const float* __restrict__ bb,
    const float* __restrict__ bc, const float* __restrict__ vwp,
    float* __restrict__ outf, u16* __restrict__ outb,
    int N, int ldA, int ldW, long stepA, long stepW, int nsteps, int zA) {
  __shared__ __align__(16) char smem[49152];
  gemm_body<EPI, RELU>(smem, blockIdx.x, blockIdx.y, blockIdx.z, A0, W0,
                       ba, bb, bc, vwp, outf, outb, N, ldA, ldW, stepA,
                       stepW, nsteps, zA);
}

__global__ __launch_bounds__(256) void attn_pv(
    const u16* __restrict__ energy, const u16* __restrict__ VT,
    const int* __restrict__ mask, u16* __restrict__ attno) {
  __shared__ __align__(16) char smem[49152];
  attn_body(smem, blockIdx.x, blockIdx.y, energy, VT, mask, attno);
}

template <bool DUAL, int NX>
__global__ __launch_bounds__(256) void add_ln(
    const float* __restrict__ x, const float* __restrict__ res,
    const float* __restrict__ g, const float* __restrict__ bt,
    float* __restrict__ outf, u16* __restrict__ outb) {
  __shared__ __align__(16) char smem[2048];
  ln_body<DUAL, NX>(smem, blockIdx.x, x, res, g, bt, outf, outb);
}

// ===========================================================================
extern "C" void kernel_launch(void* const* d_in, const int* in_sizes, int n_in,
                              void* d_out, int out_size, void* d_ws, size_t ws_size,
                              hipStream_t stream) {
  const float* src   = (const float*)d_in[0];
  const int*   mask  = (const int*)d_in[1];
  const float* Wq = (const float*)d_in[2];  const float* bq = (const float*)d_in[3];
  const float* Wk = (const float*)d_in[4];  const float* bk = (const float*)d_in[5];
  const float* Wv = (const float*)d_in[6];  const float* bv = (const float*)d_in[7];
  const float* Ww = (const float*)d_in[8];  const float* bw = (const float*)d_in[9];
  const float* Wu = (const float*)d_in[10]; const float* bu = (const float*)d_in[11];
  const float* vw = (const float*)d_in[12]; const float* vb = (const float*)d_in[13];
  const float* Wo = (const float*)d_in[14]; const float* bo = (const float*)d_in[15];
  const float* g1 = (const float*)d_in[16]; const float* b1n = (const float*)d_in[17];
  const float* g2 = (const float*)d_in[18]; const float* b2n = (const float*)d_in[19];
  const float* W1 = (const float*)d_in[20]; const float* bf1 = (const float*)d_in[21];
  const float* W2 = (const float*)d_in[22]; const float* bf2 = (const float*)d_in[23];
  float* out = (float*)d_out;

  char* wsb = (char*)d_ws;
  const size_t MB = 1024 * 1024;
  u16*   srcb  = (u16*)(wsb);
  u16*   Wcat  = (u16*)(wsb + 1 * MB);
  u16*   Wqp   = Wcat;
  u16*   Wkp   = Wcat + 262144;
  u16*   Wob   = (u16*)(wsb + 5 * MB / 2);
  u16*   W1b   = (u16*)(wsb + 3 * MB);
  u16*   W2b   = (u16*)(wsb + 5 * MB);
  float* bqp   = (float*)(wsb + 7 * MB);
  float* bkp   = (float*)(wsb + 7 * MB + 8192);
  u16*   VT    = (u16*)(wsb + 8 * MB);
  u16*   Qf    = (u16*)(wsb + 9 * MB);
  u16*   Kf    = (u16*)(wsb + 14 * MB);
  u16*   energyb = (u16*)(wsb + 19 * MB);
  u16*   attno = (u16*)(wsb + 27 * MB);
  float* woout = (float*)(wsb + 28 * MB);
  float* ln1f  = (float*)(wsb + 32 * MB);
  u16*   ln1b  = (u16*)(wsb + 34 * MB);
  u16*   hb    = (u16*)(wsb + 35 * MB);
  float* ffn2f = (float*)(wsb + 39 * MB);

  // --- preferred path: one cooperative mega-kernel ---
  P24 prm = {src, mask, Wq, bq, Wk, bk, Wv, bv, Ww, bw, Wu, bu, vw, vb,
             Wo, bo, g1, b1n, g2, b2n, W1, bf1, W2, bf2, out, wsb};
  void* kargs[] = {(void*)&prm};
  hipError_t e = hipLaunchCooperativeKernel(
      reinterpret_cast<void*>(mega), dim3(MEGA_GRID), dim3(256), kargs, 0, stream);
  if (e == hipSuccess) return;
  (void)hipGetLastError();  // clear error, fall back to multi-launch path

  // --- fallback: R11 9-dispatch sequence ---
  dim3 blk(256);
  prep_all<<<dim3(1024, 8), blk, 0, stream>>>(
      src, Wv, Wo, W1, W2, srcb, Wcat + 524288, Wob, W1b, W2b,
      Ww, Wq, bw, bq, Wu, Wk, bu, bk, Wqp, Wkp, bqp, bkp, Qf);
  gemm64<2, false><<<dim3(24, 16), blk, 0, stream>>>(
      srcb, Wcat, bqp, bkp, bv, vw, (float*)VT, Qf, 1536, 512, 512, 64, 64, 8, 0);
  gemm64<5, false><<<dim3(8, 8, 16), blk, 0, stream>>>(
      Qf, Kf, nullptr, nullptr, nullptr, nullptr, nullptr, energyb,
      512, 64, 64, 524288, 524288, 5, 0);
  attn_pv<<<dim3(16, 16), blk, 0, stream>>>(energyb, VT, mask, attno);
  gemm64<6, false><<<dim3(8, 16, 2), blk, 0, stream>>>(
      attno, Wob, bo, nullptr, nullptr, nullptr, woout, nullptr,
      512, 512, 512, 64, 64, 4, 256);
  add_ln<true, 2><<<dim3(1024), blk, 0, stream>>>(woout, src, g1, b1n, ln1f, ln1b);
  gemm64<1, true><<<dim3(32, 16), blk, 0, stream>>>(
      ln1b, W1b, bf1, nullptr, nullptr, nullptr, nullptr, hb,
      2048, 512, 512, 64, 64, 8, 0);
  gemm64<6, false><<<dim3(8, 16, 4), blk, 0, stream>>>(
      hb, W2b, bf2, nullptr, nullptr, nullptr, ffn2f, nullptr,
      512, 2048, 2048, 64, 64, 8, 512);
  add_ln<false, 4><<<dim3(1024), blk, 0, stream>>>(ffn2f, ln1f, g2, b2n, out, nullptr);
}

// Round 13
// 92.252 us; speedup vs baseline: 6.0349x; 6.0349x over previous
//
#include <hip/hip_runtime.h>
#include <hip/hip_bf16.h>
#include <math.h>

#define HID 512
#define HEADS 8
#define HD 64
#define L 512
#define B 2
#define PF 2048
#define EPS 1e-5f
#define LOG2E 1.4426950408889634f

// degree-5 odd tanh fit on [-0.8,0.8], max err ~2e-4 in range
#define TD1 0.999253f
#define TD3 -0.321476f
#define TD5 0.089206f

typedef short v8s __attribute__((ext_vector_type(8)));
typedef short v4s __attribute__((ext_vector_type(4)));
typedef float f32x4 __attribute__((ext_vector_type(4)));
typedef unsigned short u16;

// async global->LDS, 16B per lane; LDS dest = wave-uniform base + lane*16
#define GL2LDS16(gp, lp) __builtin_amdgcn_global_load_lds( \
    (const __attribute__((address_space(1))) unsigned int*)(gp), \
    (__attribute__((address_space(3))) unsigned int*)(lp), 16, 0, 0)

__device__ __forceinline__ u16 f2bf(float f) {
  union { float f; unsigned u; } v;
  v.f = f;
  unsigned r = v.u + 0x7FFFu + ((v.u >> 16) & 1u);
  return (u16)(r >> 16);
}

__device__ __forceinline__ float bf2f(u16 b) {
  union { unsigned u; float f; } v;
  v.u = ((unsigned)b) << 16;
  return v.f;
}

// ---------------------------------------------------------------------------
// prep_all: (a) fp32->bf16 of src,Wv,Wo,W1,W2 (y=0..4), (b) weight folding
// Wqp/Wkp + biases (y=5,6), (c) Qf ones-plane fill (y=7).
// ---------------------------------------------------------------------------
__global__ __launch_bounds__(256) void prep_all(
    const float* __restrict__ s0, const float* __restrict__ s1,
    const float* __restrict__ s2, const float* __restrict__ s3,
    const float* __restrict__ s4,
    u16* d0, u16* d1, u16* d2, u16* d3, u16* d4,
    const float* __restrict__ Ww, const float* __restrict__ Wq,
    const float* __restrict__ bw, const float* __restrict__ bq,
    const float* __restrict__ Wu, const float* __restrict__ Wk,
    const float* __restrict__ bu, const float* __restrict__ bk,
    u16* __restrict__ Wqp, u16* __restrict__ Wkp,
    float* __restrict__ bqp, float* __restrict__ bkp,
    u16* __restrict__ Qf) {
  const int y = blockIdx.y;
  const int t = threadIdx.x;
  if (y < 5) {
    const float* s; u16* d; int n;
    switch (y) {
      case 0: s = s0; d = d0; n = 524288; break;
      case 1: s = s1; d = d1; n = 262144; break;
      case 2: s = s2; d = d2; n = 262144; break;
      case 3: s = s3; d = d3; n = 1048576; break;
      default: s = s4; d = d4; n = 1048576; break;
    }
    int idx = (blockIdx.x * 256 + t) * 4;
    if (idx >= n) return;
    float4 v = *(const float4*)&s[idx];
    v4s o;
    o[0] = (short)f2bf(v.x); o[1] = (short)f2bf(v.y);
    o[2] = (short)f2bf(v.z); o[3] = (short)f2bf(v.w);
    *(v4s*)&d[idx] = o;
  } else if (y < 7) {
    const int hi = blockIdx.x;
    if (hi >= 512) return;
    const int h = hi >> 6, i = hi & 63;
    const bool isK = (y == 6);
    const float* Ws = isK ? Wu : Ww;
    const float* Wb = isK ? Wk : Wq;
    const float* bs = isK ? bu : bw;
    const float* bb2 = isK ? bk : bq;
    u16* ow = isK ? Wkp : Wqp;
    float* ob = isK ? bkp : bqp;
    __shared__ float wrow[64];
    if (t < 64) wrow[t] = Ws[i * 64 + t];
    __syncthreads();
    float a0 = 0.f, a1 = 0.f;
    for (int j = 0; j < 64; j++) {
      const float w = wrow[j];
      a0 = fmaf(w, Wb[(size_t)(h * 64 + j) * 512 + t], a0);
      a1 = fmaf(w, Wb[(size_t)(h * 64 + j) * 512 + t + 256], a1);
    }
    ow[(size_t)hi * 512 + t] = f2bf(a0);
    ow[(size_t)hi * 512 + t + 256] = f2bf(a1);
    if (t == 0) {
      float s = bs[i];
      for (int j = 0; j < 64; j++) s = fmaf(wrow[j], bb2[h * 64 + j], s);
      ob[hi] = s;
    }
  } else {
    int idx = (blockIdx.x * 256 + t) * 4;
    if (idx >= 524288) return;
    v4s o;
    o[0] = o[1] = o[2] = o[3] = (short)0x3F80;
    *(v4s*)&Qf[idx] = o;
  }
}

// ---------------------------------------------------------------------------
// 64x64-tile MFMA GEMM, 3-deep LDS pipeline + counted vmcnt.
// 1-D grid with chunked XCD swizzle + 4x4 supertiling:
//   wg = (bid%8)*(total/8) + bid/8  ->  each XCD gets a contiguous wg chunk;
//   wg decodes z-major-last + 4x4 supertiles, so blocks co-resident on an
//   XCD share operand panels (energy: 2 bh's Qf/Kf = 1.3MB stays in 4MB L2).
// Requires total%8==0, gx%4==0, gy%4==0.
// EPI: 0 = f32 row-major + bias
//      1 = bf16 row-major + bias (+RELU)
//      2 = proj+feats: region (bn>>9): 0 -> Qf planes 1..4, 1 -> Kf planes
//          0..4 (needs vwp), 2 -> VT bf16 [bh][d][q]
//      5 = energy: plane layout, z = bh; bf16 out [z][512][512], no bias
//      6 = K-split partial: z = K-chunk of zA; f32 out + bias on z==0
// ---------------------------------------------------------------------------
template <int EPI, bool RELU>
__global__ __launch_bounds__(256) void gemm64(
    const u16* __restrict__ A0, const u16* __restrict__ W0,
    const float* __restrict__ ba, const float* __restrict__ bb,
    const float* __restrict__ bc, const float* __restrict__ vwp,
    float* __restrict__ outf, u16* __restrict__ outb,
    int N, int gx, int gy, int ldA, int ldW, long stepA, long stepW,
    int nsteps, int zA) {
  const int t = threadIdx.x;
  // --- XCD-chunked swizzle + supertile decode ---
  const int total = gridDim.x;
  int wg = ((int)blockIdx.x & 7) * (total >> 3) + ((int)blockIdx.x >> 3);
  const int xy = gx * gy;
  const int z = wg / xy;
  const int rem = wg - z * xy;
  const int st = rem >> 4, w = rem & 15;
  const int sgx = gx >> 2;
  const int bx = (st % sgx) * 4 + (w & 3);
  const int by = (st / sgx) * 4 + (w >> 2);

  const u16* A = A0;
  const u16* W = W0;
  float* of = outf;
  u16* ob = outb;
  if (EPI == 5) {
    A += (size_t)z * 32768;   // z*512 rows within plane (ld 64)
    W += (size_t)z * 32768;
    ob += (size_t)z * 262144;
  } else if (EPI == 6) {
    A += (size_t)z * zA;      // K offset
    W += (size_t)z * zA;
    of += (size_t)z * 524288; // partial buffer
  }

  __shared__ __align__(16) u16 Al[3][8][64][8];   // 24KB
  __shared__ __align__(16) u16 Bl[3][8][64][8];   // 24KB

  const int bm = by * 64, bn = bx * 64;
  const int lane = t & 63, wv = t >> 6;
  const int wr = wv >> 1, wc = wv & 1;
  const int lg = lane >> 4, lr = lane & 15;

  const u16* Asrc = A + (size_t)(bm + lane) * ldA + wv * 8;
  const u16* Bsrc = W + (size_t)(bn + lane) * ldW + wv * 8;

  f32x4 zero = {0.f, 0.f, 0.f, 0.f};
  f32x4 acc[2][2] = {{zero, zero}, {zero, zero}};

#define STAGE(tt) do {                                   \
    const long oA = (long)(tt) * stepA;                  \
    const long oW = (long)(tt) * stepW;                  \
    const int bi_ = (tt) % 3;                            \
    GL2LDS16(Asrc + oA,      &Al[bi_][wv][0][0]);        \
    GL2LDS16(Asrc + oA + 32, &Al[bi_][wv + 4][0][0]);    \
    GL2LDS16(Bsrc + oW,      &Bl[bi_][wv][0][0]);        \
    GL2LDS16(Bsrc + oW + 32, &Bl[bi_][wv + 4][0][0]);    \
  } while (0)

  STAGE(0);
  if (nsteps > 1) STAGE(1);

  for (int s = 0; s < nsteps; s++) {
    if (s + 1 < nsteps) {
      asm volatile("s_waitcnt vmcnt(4)" ::: "memory");
    } else {
      asm volatile("s_waitcnt vmcnt(0)" ::: "memory");
    }
    __builtin_amdgcn_s_barrier();
    if (s + 2 < nsteps) STAGE(s + 2);

    const int cur = s % 3;
    #pragma unroll
    for (int hf = 0; hf < 2; hf++) {
      v8s a0 = *(const v8s*)&Al[cur][hf * 4 + lg][wr * 32 + lr][0];
      v8s a1 = *(const v8s*)&Al[cur][hf * 4 + lg][wr * 32 + 16 + lr][0];
      v8s b0 = *(const v8s*)&Bl[cur][hf * 4 + lg][wc * 32 + lr][0];
      v8s b1 = *(const v8s*)&Bl[cur][hf * 4 + lg][wc * 32 + 16 + lr][0];
      acc[0][0] = __builtin_amdgcn_mfma_f32_16x16x32_bf16(a0, b0, acc[0][0], 0, 0, 0);
      acc[0][1] = __builtin_amdgcn_mfma_f32_16x16x32_bf16(a0, b1, acc[0][1], 0, 0, 0);
      acc[1][0] = __builtin_amdgcn_mfma_f32_16x16x32_bf16(a1, b0, acc[1][0], 0, 0, 0);
      acc[1][1] = __builtin_amdgcn_mfma_f32_16x16x32_bf16(a1, b1, acc[1][1], 0, 0, 0);
    }
  }
#undef STAGE

  #pragma unroll
  for (int m = 0; m < 2; m++) {
    #pragma unroll
    for (int n = 0; n < 2; n++) {
      const int gm0 = bm + wr * 32 + m * 16 + lg * 4;
      const int gn = bn + wc * 32 + n * 16 + lr;
      if (EPI == 0) {
        const float bvv = ba[gn];
        #pragma unroll
        for (int r = 0; r < 4; r++)
          of[(size_t)(gm0 + r) * N + gn] = acc[m][n][r] + bvv;
      } else if (EPI == 1) {
        const float bvv = ba[gn];
        #pragma unroll
        for (int r = 0; r < 4; r++) {
          float v = acc[m][n][r] + bvv;
          if (RELU) v = fmaxf(v, 0.f);
          ob[(size_t)(gm0 + r) * N + gn] = f2bf(v);
        }
      } else if (EPI == 2) {
        const int region = bn >> 9;  // uniform per block
        const int np = gn & 511, h = np >> 6, d = np & 63;
        const int b_ = gm0 >> 9, q0 = gm0 & 511;
        const int bh = b_ * 8 + h;
        if (region == 0) {
          const float bvv = ba[np];
          #pragma unroll
          for (int r = 0; r < 4; r++) {
            const float u = acc[m][n][r] + bvv;
            const float u2 = u * u;
            const size_t base = ((size_t)bh * 512 + q0 + r) * 64 + d;
            ob[base + 524288]  = f2bf(u);
            ob[base + 1048576] = f2bf(u2);
            ob[base + 1572864] = f2bf(u2 * u);
            ob[base + 2097152] = f2bf(u2 * u2);
          }
        } else if (region == 1) {
          const float bvv = bb[np];
          const float w2 = vwp[d];
          u16* kf = ob + 2621440;  // Kf base (5 planes after Qf)
          #pragma unroll
          for (int r = 0; r < 4; r++) {
            const float v = acc[m][n][r] + bvv;
            const float v2 = v * v;
            const size_t base = ((size_t)bh * 512 + q0 + r) * 64 + d;
            kf[base]           = f2bf(w2 * v * fmaf(v2, fmaf(v2, TD5, TD3), TD1));
            kf[base + 524288]  = f2bf(w2 * fmaf(v2, fmaf(v2, 5.f * TD5, 3.f * TD3), TD1));
            kf[base + 1048576] = f2bf(w2 * v * fmaf(v2, 10.f * TD5, 3.f * TD3));
            kf[base + 1572864] = f2bf(w2 * fmaf(v2, 10.f * TD5, TD3));
            kf[base + 2097152] = f2bf(w2 * 5.f * TD5 * v);
          }
        } else {
          const float bvv = bc[np];
          u16* vt = (u16*)outf;
          v4s pk;
          #pragma unroll
          for (int r = 0; r < 4; r++) pk[r] = (short)f2bf(acc[m][n][r] + bvv);
          *(v4s*)&vt[((size_t)bh * 64 + d) * 512 + q0] = pk;
        }
      } else if (EPI == 5) {
        #pragma unroll
        for (int r = 0; r < 4; r++)
          ob[(size_t)(gm0 + r) * 512 + gn] = f2bf(acc[m][n][r]);
      } else {  // EPI == 6
        const float bvv = (z == 0) ? ba[gn] : 0.f;
        #pragma unroll
        for (int r = 0; r < 4; r++)
          of[(size_t)(gm0 + r) * 512 + gn] = acc[m][n][r] + bvv;
      }
    }
  }
}

// ---------------------------------------------------------------------------
// Fused softmax + PV.  1-D grid 256, XCD-chunked: 2 bh per XCD (VT resident).
// ---------------------------------------------------------------------------
__global__ __launch_bounds__(256) void attn_pv(
    const u16* __restrict__ energy, const u16* __restrict__ VT,
    const int* __restrict__ mask, u16* __restrict__ attno) {
  const int total = gridDim.x;
  int wg = ((int)blockIdx.x & 7) * (total >> 3) + ((int)blockIdx.x >> 3);
  const int qt = wg & 15;
  const int bh = wg >> 4;
  const int b = bh >> 3, h = bh & 7;
  const int t = threadIdx.x;
  const int lane = t & 63, wv = t >> 6;

  __shared__ __align__(16) u16 P[32][512];          // 32KB, slot-swizzled
  __shared__ __align__(16) u16 Bl[2][8][64][8];     // 16KB

  const u16* eb = energy + ((size_t)bh * 512 + qt * 32) * 512;
  const int mbase = b * 512 + lane * 8;
  #pragma unroll
  for (int rr = 0; rr < 8; rr++) {
    const int r = wv * 8 + rr;
    v8s ev = *(const v8s*)&eb[(size_t)r * 512 + lane * 8];
    float e[8];
    float mx = -INFINITY;
    #pragma unroll
    for (int i = 0; i < 8; i++) {
      float x = bf2f((u16)ev[i]);
      if (mask[mbase + i] == 0) x = -INFINITY;
      e[i] = x;
      mx = fmaxf(mx, x);
    }
    #pragma unroll
    for (int off = 32; off > 0; off >>= 1) mx = fmaxf(mx, __shfl_xor(mx, off));
    float sm = 0.f;
    #pragma unroll
    for (int i = 0; i < 8; i++) {
      e[i] = exp2f((e[i] - mx) * LOG2E);
      sm += e[i];
    }
    #pragma unroll
    for (int off = 32; off > 0; off >>= 1) sm += __shfl_xor(sm, off);
    const float inv = __builtin_amdgcn_rcpf(sm);
    v8s po;
    #pragma unroll
    for (int i = 0; i < 8; i++) po[i] = (short)f2bf(e[i] * inv);
    *(v8s*)&P[r][(lane ^ (r & 7)) * 8] = po;   // slot swizzle
  }
  __syncthreads();

  const int wr = wv >> 1, wc = wv & 1;
  const int lg = lane >> 4, lr = lane & 15;
  f32x4 acc0 = {0.f, 0.f, 0.f, 0.f}, acc1 = acc0;
  const u16* Bsrc = VT + ((size_t)bh * 64 + lane) * 512 + wv * 8;

  GL2LDS16(Bsrc,      &Bl[0][wv][0][0]);
  GL2LDS16(Bsrc + 32, &Bl[0][wv + 4][0][0]);
  __syncthreads();

  const int arow = wr * 16 + lr;
  const int axor = arow & 7;
  for (int s = 0; s < 8; s++) {
    const int cur = s & 1;
    if (s < 7) {
      const int k0 = (s + 1) << 6;
      GL2LDS16(Bsrc + k0,      &Bl[cur ^ 1][wv][0][0]);
      GL2LDS16(Bsrc + k0 + 32, &Bl[cur ^ 1][wv + 4][0][0]);
    }
    #pragma unroll
    for (int hf = 0; hf < 2; hf++) {
      const int bslot = s * 8 + hf * 4 + lg;
      v8s a = *(const v8s*)&P[arow][(bslot ^ axor) * 8];
      v8s b0 = *(const v8s*)&Bl[cur][hf * 4 + lg][wc * 32 + lr][0];
      v8s b1 = *(const v8s*)&Bl[cur][hf * 4 + lg][wc * 32 + 16 + lr][0];
      acc0 = __builtin_amdgcn_mfma_f32_16x16x32_bf16(a, b0, acc0, 0, 0, 0);
      acc1 = __builtin_amdgcn_mfma_f32_16x16x32_bf16(a, b1, acc1, 0, 0, 0);
    }
    __syncthreads();
  }

  const int q0 = qt * 32 + wr * 16 + lg * 4;
  #pragma unroll
  for (int n = 0; n < 2; n++) {
    f32x4 a = n ? acc1 : acc0;
    const int d = wc * 32 + n * 16 + lr;
    #pragma unroll
    for (int r = 0; r < 4; r++)
      attno[((size_t)(b * 512 + q0 + r)) * 512 + h * 64 + d] = f2bf(a[r]);
  }
}

// ---------------------------------------------------------------------------
// Fused residual add + LayerNorm; x = sum of NX partials (stride 524288).
// ---------------------------------------------------------------------------
template <bool DUAL, int NX>
__global__ __launch_bounds__(256) void add_ln(
    const float* __restrict__ x, const float* __restrict__ res,
    const float* __restrict__ g, const float* __restrict__ bt,
    float* __restrict__ outf, u16* __restrict__ outb) {
  const int row = blockIdx.x;
  const int t = threadIdx.x;
  const float* rr = res + (size_t)row * HID;

  float v0 = rr[t];
  float v1 = rr[t + 256];
  #pragma unroll
  for (int i = 0; i < NX; i++) {
    const float* xr = x + (size_t)i * 524288 + (size_t)row * HID;
    v0 += xr[t];
    v1 += xr[t + 256];
  }

  __shared__ float rs[256], rss[256];
  rs[t] = v0 + v1;
  rss[t] = v0 * v0 + v1 * v1;
  __syncthreads();
  for (int off = 128; off > 0; off >>= 1) {
    if (t < off) {
      rs[t] += rs[t + off];
      rss[t] += rss[t + off];
    }
    __syncthreads();
  }
  const float mean = rs[0] * (1.f / HID);
  const float var = rss[0] * (1.f / HID) - mean * mean;
  const float inv = rsqrtf(var + EPS);

  float o0 = (v0 - mean) * inv * g[t] + bt[t];
  float o1 = (v1 - mean) * inv * g[t + 256] + bt[t + 256];
  outf[(size_t)row * HID + t] = o0;
  outf[(size_t)row * HID + t + 256] = o1;
  if (DUAL) {
    outb[(size_t)row * HID + t] = f2bf(o0);
    outb[(size_t)row * HID + t + 256] = f2bf(o1);
  }
}

// ---------------------------------------------------------------------------
extern "C" void kernel_launch(void* const* d_in, const int* in_sizes, int n_in,
                              void* d_out, int out_size, void* d_ws, size_t ws_size,
                              hipStream_t stream) {
  const float* src   = (const float*)d_in[0];
  const int*   mask  = (const int*)d_in[1];
  const float* Wq = (const float*)d_in[2];  const float* bq = (const float*)d_in[3];
  const float* Wk = (const float*)d_in[4];  const float* bk = (const float*)d_in[5];
  const float* Wv = (const float*)d_in[6];  const float* bv = (const float*)d_in[7];
  const float* Ww = (const float*)d_in[8];  const float* bw = (const float*)d_in[9];
  const float* Wu = (const float*)d_in[10]; const float* bu = (const float*)d_in[11];
  const float* vw = (const float*)d_in[12]; const float* vb = (const float*)d_in[13];
  const float* Wo = (const float*)d_in[14]; const float* bo = (const float*)d_in[15];
  const float* g1 = (const float*)d_in[16]; const float* b1n = (const float*)d_in[17];
  const float* g2 = (const float*)d_in[18]; const float* b2n = (const float*)d_in[19];
  const float* W1 = (const float*)d_in[20]; const float* bf1 = (const float*)d_in[21];
  const float* W2 = (const float*)d_in[22]; const float* bf2 = (const float*)d_in[23];
  float* out = (float*)d_out;
  (void)vb;  // constant shift cancels in softmax

  char* wsb = (char*)d_ws;
  const size_t MB = 1024 * 1024;
  u16*   srcb  = (u16*)(wsb);
  u16*   Wcat  = (u16*)(wsb + 1 * MB);
  u16*   Wqp   = Wcat;
  u16*   Wkp   = Wcat + 262144;
  u16*   Wob   = (u16*)(wsb + 5 * MB / 2);
  u16*   W1b   = (u16*)(wsb + 3 * MB);
  u16*   W2b   = (u16*)(wsb + 5 * MB);
  float* bqp   = (float*)(wsb + 7 * MB);
  float* bkp   = (float*)(wsb + 7 * MB + 8192);
  u16*   VT    = (u16*)(wsb + 8 * MB);
  u16*   Qf    = (u16*)(wsb + 9 * MB);
  u16*   Kf    = (u16*)(wsb + 14 * MB);
  u16*   energyb = (u16*)(wsb + 19 * MB);
  u16*   attno = (u16*)(wsb + 27 * MB);
  float* woout = (float*)(wsb + 28 * MB);   // 2 partials (4MB)
  float* ln1f  = (float*)(wsb + 32 * MB);
  u16*   ln1b  = (u16*)(wsb + 34 * MB);
  u16*   hb    = (u16*)(wsb + 35 * MB);
  float* ffn2f = (float*)(wsb + 39 * MB);   // 4 partials (8MB)
  (void)Kf;

  dim3 blk(256);

  // 1) convert + weight-fold + ones-plane
  prep_all<<<dim3(1024, 8), blk, 0, stream>>>(
      src, Wv, Wo, W1, W2, srcb, Wcat + 524288, Wob, W1b, W2b,
      Ww, Wq, bw, bq, Wu, Wk, bu, bk, Wqp, Wkp, bqp, bkp, Qf);

  // 2) fused projection: src @ [Wqp;Wkp;Wv]^T -> Qf planes, Kf planes, VT
  gemm64<2, false><<<dim3(384), blk, 0, stream>>>(
      srcb, Wcat, bqp, bkp, bv, vw, (float*)VT, Qf,
      1536, 24, 16, 512, 512, 64, 64, 8, 0);

  // 3) energy = Qfeat @ Kfeat^T (batched per bh), K=320 -> bf16
  //    XCD-chunked: 2 bh per XCD -> Qf/Kf panels L2-resident
  gemm64<5, false><<<dim3(1024), blk, 0, stream>>>(
      Qf, Kf, nullptr, nullptr, nullptr, nullptr, nullptr, energyb,
      512, 8, 8, 64, 64, 524288, 524288, 5, 0);

  // 4) fused softmax + PV -> merged-head attno bf16
  attn_pv<<<dim3(256), blk, 0, stream>>>(energyb, VT, mask, attno);

  // 5) Wo, K-split z=2 -> two f32 partials
  gemm64<6, false><<<dim3(256), blk, 0, stream>>>(
      attno, Wob, bo, nullptr, nullptr, nullptr, woout, nullptr,
      512, 8, 16, 512, 512, 64, 64, 4, 256);

  // 6) residual + LN1 (sums 2 partials)
  add_ln<true, 2><<<dim3(1024), blk, 0, stream>>>(woout, src, g1, b1n, ln1f, ln1b);

  // 7) FFN1 (relu) -> bf16
  gemm64<1, true><<<dim3(512), blk, 0, stream>>>(
      ln1b, W1b, bf1, nullptr, nullptr, nullptr, nullptr, hb,
      2048, 32, 16, 512, 512, 64, 64, 8, 0);

  // 8) FFN2, K-split z=4 -> four f32 partials (A row stride 2048)
  gemm64<6, false><<<dim3(512), blk, 0, stream>>>(
      hb, W2b, bf2, nullptr, nullptr, nullptr, ffn2f, nullptr,
      512, 8, 16, 2048, 2048, 64, 64, 8, 512);

  // 9) residual + LN2 (sums 4 partials) -> out
  add_ln<false, 4><<<dim3(1024), blk, 0, stream>>>(ffn2f, ln1f, g2, b2n, out, nullptr);
}